// Round 5
// baseline (34.010 us; speedup 1.0000x reference)
//
#include <hip/hip_runtime.h>

// WHXE loss, round 5: global_load_lds triple-buffered prefetch (zero-VGPR MLP).
//   colS[n] = sum_b lam[n] * logp[b,n] * true[b,n]
//   cnt[n]  = sum_b true[b,n]
//   loss    = -(1/B) * sum_n (B / (N*(cnt[n]+eps))) * colS[n]
// Sibling groups are 4 consecutive columns -> one float4 = one softmax group.
//
// Key structural fact: thread t's staged bytes land at slot_base + t*16
// (global_load_lds writes wave-uniform-base + lane*16) and are read back ONLY
// by thread t -> no __syncthreads in the main loop; vmcnt (wave-scoped)
// provides all ordering. Triple-buffer avoids WAR on slots.
// LESSONS: (R3) no per-block device-scope fences; (R4) compiler refuses to
// keep VGPR-staged load batches in flight -> use LDS-DMA instead.

#define B_TOTAL 131072
#define N_NODES 128
#define ALPHA   0.5f
#define EPS     1e-10f

constexpr int BLOCKS         = 2048;
constexpr int THREADS        = 256;
constexpr int ROWS_PER_BLOCK = B_TOTAL / BLOCKS;          // 64
constexpr int TILE_ROWS      = 8;
constexpr int NT             = ROWS_PER_BLOCK / TILE_ROWS; // 8 tiles/block
constexpr int SLOT_FLOATS    = 2 * TILE_ROWS * N_NODES;    // 2048 (logits+true)
constexpr int SLOTS          = 3;                          // 24 KB LDS
constexpr int REPLICAS       = 32;

typedef const __attribute__((address_space(1))) void* gas_t;
typedef __attribute__((address_space(3)))       void* las_t;

__global__ __launch_bounds__(THREADS) void whxe_pass1(
    const float* __restrict__ logits,
    const float* __restrict__ truev,
    const float* __restrict__ depths,
    float* __restrict__ ws)   // ws[rep][256]: [0..127]=colS, [128..255]=cnt
{
    __shared__ float lds[SLOTS * SLOT_FLOATS];

    const int t  = threadIdx.x;
    const int wv = t >> 6;            // wave 0..3
    const int cg = t & 31;            // column group (4 cols each)
    const int c0 = cg << 2;

    float lam[4];
#pragma unroll
    for (int i = 0; i < 4; ++i) lam[i] = __expf(-ALPHA * depths[c0 + i]);

    // thread t owns tile element range [t*4, t*4+4) (floats); within a tile
    // that is row (t>>5), cols c0..c0+3 — same mapping as the proven R2 kernel.
    const size_t blk = (size_t)blockIdx.x * ROWS_PER_BLOCK * N_NODES;
    const float* gl = logits + blk + t * 4;   // per-lane global src
    const float* gt = truev  + blk + t * 4;

    // stage tile k into slot k%SLOTS: two 1KB/wave DMA writes, zero VGPR cost
#define STAGE(k)                                                              \
    do {                                                                      \
        float* lb = &lds[((k) % SLOTS) * SLOT_FLOATS + wv * 256];             \
        __builtin_amdgcn_global_load_lds((gas_t)(gl + (size_t)(k) * 1024),    \
                                         (las_t)lb,           16, 0, 0);      \
        __builtin_amdgcn_global_load_lds((gas_t)(gt + (size_t)(k) * 1024),    \
                                         (las_t)(lb + 1024),  16, 0, 0);      \
    } while (0)

    STAGE(0);
    STAGE(1);

    float colS[4] = {0.f, 0.f, 0.f, 0.f};
    float cnt [4] = {0.f, 0.f, 0.f, 0.f};

#pragma unroll
    for (int k = 0; k < NT; ++k) {
        if (k + 2 < NT) STAGE(k + 2);
        // counted waits: oldest 2 (tile k's) must be done; never drain to 0
        if      (k < NT - 2) asm volatile("s_waitcnt vmcnt(4)" ::: "memory");
        else if (k == NT - 2) asm volatile("s_waitcnt vmcnt(2)" ::: "memory");
        else                  asm volatile("s_waitcnt vmcnt(0)" ::: "memory");
        __builtin_amdgcn_sched_barrier(0);   // rule #18: pin reads below wait

        const int s4 = (k % SLOTS) * SLOT_FLOATS + t * 4;
        const float4 x  = *reinterpret_cast<const float4*>(&lds[s4]);
        const float4 tv = *reinterpret_cast<const float4*>(&lds[s4 + 1024]);

        const float e0 = __expf(x.x), e1 = __expf(x.y),
                    e2 = __expf(x.z), e3 = __expf(x.w);
        const float ld = __logf(e0 + e1 + e2 + e3 + EPS);
        colS[0] += lam[0] * (x.x - ld) * tv.x;  cnt[0] += tv.x;
        colS[1] += lam[1] * (x.y - ld) * tv.y;  cnt[1] += tv.y;
        colS[2] += lam[2] * (x.z - ld) * tv.z;  cnt[2] += tv.z;
        colS[3] += lam[3] * (x.w - ld) * tv.w;  cnt[3] += tv.w;
    }
#undef STAGE

    // block reduction (reuse slot 0 LDS): 8 accums/thread -> 256 partials
    __syncthreads();
#pragma unroll
    for (int i = 0; i < 4; ++i) {
        lds[i * 256 + t]       = colS[i];
        lds[(4 + i) * 256 + t] = cnt[i];
    }
    __syncthreads();

    const int q   = t >> 7;           // 0 = colS, 1 = cnt
    const int c   = t & 127;          // column
    const int acc = q * 4 + (c & 3);
    const int cgr = c >> 2;
    float s = 0.f;
#pragma unroll
    for (int r = 0; r < 8; ++r) s += lds[acc * 256 + r * 32 + cgr];

    const int rep = blockIdx.x & (REPLICAS - 1);
    atomicAdd(&ws[rep * 256 + q * 128 + c], s);
}

__global__ __launch_bounds__(256) void whxe_pass2(
    const float* __restrict__ ws, float* __restrict__ out)
{
    const int t = threadIdx.x;        // 256
    float s = 0.f;
#pragma unroll
    for (int r = 0; r < REPLICAS; ++r) s += ws[r * 256 + t];

    __shared__ float red[256];
    red[t] = s;
    __syncthreads();

    if (t < 64) {
        float v = 0.f;
#pragma unroll
        for (int cc = t; cc < 128; cc += 64) {
            const float w = (float)B_TOTAL / ((float)N_NODES * (red[128 + cc] + EPS));
            v += w * red[cc];
        }
#pragma unroll
        for (int off = 32; off; off >>= 1) v += __shfl_xor(v, off);
        if (t == 0) out[0] = -v / (float)B_TOTAL;
    }
}

extern "C" void kernel_launch(void* const* d_in, const int* in_sizes, int n_in,
                              void* d_out, int out_size, void* d_ws, size_t ws_size,
                              hipStream_t stream) {
    const float* logits = (const float*)d_in[0];
    const float* truev  = (const float*)d_in[1];
    const float* depths = (const float*)d_in[2];
    float* ws = (float*)d_ws;

    hipMemsetAsync(ws, 0, REPLICAS * 256 * sizeof(float), stream);
    whxe_pass1<<<BLOCKS, THREADS, 0, stream>>>(logits, truev, depths, ws);
    whxe_pass2<<<1, 256, 0, stream>>>(ws, (float*)d_out);
}